// Round 1
// baseline (5050.370 us; speedup 1.0000x reference)
//
#include <hip/hip_runtime.h>
#include <math.h>

#define TT 2048

// Reduced exchangeable-class Kalman filter.
// Classes k = 2*(j>=64) + (j&1), 32 channels each. h_k = state index 0,0,2,2.
__global__ __launch_bounds__(64, 1)
void hmm_kernel(const float* __restrict__ track,
                const float* __restrict__ bias_scales,
                const float* __restrict__ obs_noise_p,
                const float* __restrict__ trans_noise_p,
                float* __restrict__ out)
{
    const double sg2 = (double)obs_noise_p[0] * (double)obs_noise_p[0];
    const double qn2 = (double)trans_noise_p[0] * (double)trans_noise_p[0];
    const double LOG2PI = 1.8378770664093454835606594728112;
    const double LN2    = 0.69314718055994530941723212145818;

    // Qs = trans_noise^2 * NCV_Q
    double Qs[4][4];
    {
        const double q13 = qn2 * (1.0/3.0), qh = 0.5 * qn2;
        Qs[0][0]=q13; Qs[0][1]=0.0; Qs[0][2]=qh;  Qs[0][3]=0.0;
        Qs[1][0]=0.0; Qs[1][1]=q13; Qs[1][2]=0.0; Qs[1][3]=qh;
        Qs[2][0]=qh;  Qs[2][1]=0.0; Qs[2][2]=qn2; Qs[2][3]=0.0;
        Qs[3][0]=0.0; Qs[3][1]=qh;  Qs[3][2]=0.0; Qs[3][3]=qn2;
    }

    const double a0c0 = (double)bias_scales[0];
    const double a0c1 = (double)bias_scales[1];

    double mu[4] = {0.0,0.0,0.0,0.0};     // class bias means
    double ms[4] = {0.0,0.0,0.0,0.0};     // NCV state mean
    double a[4]  = {a0c0, a0c1, a0c0, a0c1}; // per-class residual variance
    double B[4][4] = {{0}};               // class-block of Pbb
    double C[4][4] = {{0}};               // class x state cross-cov
    double Ps[4][4] = {{1,0,0,0},{0,1,0,0},{0,0,1,0},{0,0,0,1}};

    double sum_quad = 0.0;
    double det_m = 1.0;   // running det(I+MN) mantissa in [0.5,1)
    double det_e = 0.0;   // running exponent

    for (int t = 0; t < TT; ++t) {
        const double x0 = (double)track[2*t+0];
        const double x1 = (double)track[2*t+1];

        // ---------- predict ----------
        ms[0] += ms[2]; ms[1] += ms[3];
        #pragma unroll
        for (int k = 0; k < 4; ++k) { C[k][0] += C[k][2]; C[k][1] += C[k][3]; }
        #pragma unroll
        for (int j = 0; j < 4; ++j) { Ps[0][j] += Ps[2][j]; Ps[1][j] += Ps[3][j]; }
        #pragma unroll
        for (int i = 0; i < 4; ++i) { Ps[i][0] += Ps[i][2]; Ps[i][1] += Ps[i][3]; }
        #pragma unroll
        for (int i = 0; i < 4; ++i)
            #pragma unroll
            for (int j = 0; j < 4; ++j) Ps[i][j] += Qs[i][j];

        // ---------- per-class scalars ----------
        double dinv[4], atil[4], Nk[4], nu[4];
        #pragma unroll
        for (int k = 0; k < 4; ++k) {
            double dk = a[k] + sg2;
            dinv[k] = 1.0 / dk;
            atil[k] = a[k] * dinv[k];
            Nk[k]   = 32.0 * dinv[k];
        }
        nu[0] = x0 - mu[0] - ms[0];
        nu[1] = x1 - mu[1] - ms[0];
        nu[2] = x0 - mu[2] - ms[2];
        nu[3] = x1 - mu[3] - ms[2];

        // ---------- structured blocks ----------
        // V = C + Hc*Ps (rows), U = B + Hc*C^T, M = U + V*Hc^T (symmetric)
        double V[4][4], U[4][4], M[4][4];
        #pragma unroll
        for (int k = 0; k < 4; ++k) {
            const int hk = (k < 2) ? 0 : 2;
            #pragma unroll
            for (int c2 = 0; c2 < 4; ++c2) V[k][c2] = C[k][c2] + Ps[hk][c2];
        }
        #pragma unroll
        for (int k = 0; k < 4; ++k) {
            const int hk = (k < 2) ? 0 : 2;
            #pragma unroll
            for (int kp = 0; kp < 4; ++kp) {
                const int hkp = (kp < 2) ? 0 : 2;
                U[k][kp] = B[k][kp] + C[kp][hk];
                M[k][kp] = U[k][kp] + V[k][hkp];
            }
        }

        // A = I + M*diag(Nk) ; G2 = U - M*diag(atil)
        double A[4][4], K[4][4], G2[4][4];
        #pragma unroll
        for (int i = 0; i < 4; ++i)
            #pragma unroll
            for (int j = 0; j < 4; ++j) {
                A[i][j]  = ((i==j) ? 1.0 : 0.0) + M[i][j] * Nk[j];
                G2[i][j] = U[i][j] - M[i][j] * atil[j];
                K[i][j]  = (i==j) ? 1.0 : 0.0;
            }

        // Gauss-Jordan inverse of A -> K ; pivots are positive (eigs >= 1)
        double det_step = 1.0;
        #pragma unroll
        for (int p = 0; p < 4; ++p) {
            double piv = A[p][p];
            det_step *= piv;
            double ip = 1.0 / piv;
            #pragma unroll
            for (int j = 0; j < 4; ++j) { A[p][j] *= ip; K[p][j] *= ip; }
            #pragma unroll
            for (int r = 0; r < 4; ++r) {
                if (r == p) continue;
                double f = A[r][p];
                #pragma unroll
                for (int j = 0; j < 4; ++j) { A[r][j] -= f * A[p][j]; K[r][j] -= f * K[p][j]; }
            }
        }
        det_m *= det_step;
        { int ex; det_m = frexp(det_m, &ex); det_e += (double)ex; }

        // ---------- products ----------
        double KG2[4][4], KU[4][4], KV[4][4], Knu[4];
        #pragma unroll
        for (int i = 0; i < 4; ++i) {
            #pragma unroll
            for (int j = 0; j < 4; ++j) {
                double p1 = 0.0, p2 = 0.0, p3 = 0.0;
                #pragma unroll
                for (int r = 0; r < 4; ++r) {
                    p1 += K[i][r] * G2[r][j];
                    p2 += K[i][r] * U[r][j];
                    p3 += K[i][r] * V[r][j];
                }
                KG2[i][j] = p1; KU[i][j] = p2; KV[i][j] = p3;
            }
            double pn = 0.0;
            #pragma unroll
            for (int r = 0; r < 4; ++r) pn += K[i][r] * nu[r];
            Knu[i] = pn;
        }

        double UN[4][4], VN[4][4];
        #pragma unroll
        for (int r = 0; r < 4; ++r)
            #pragma unroll
            for (int i = 0; i < 4; ++i) { UN[r][i] = U[r][i]*Nk[r]; VN[r][i] = V[r][i]*Nk[r]; }

        // T4 = (diag(atil) + U^T diag(Nk)) * K
        double T4[4][4];
        #pragma unroll
        for (int i = 0; i < 4; ++i)
            #pragma unroll
            for (int j = 0; j < 4; ++j) {
                double s = atil[i]*K[i][j];
                #pragma unroll
                for (int r = 0; r < 4; ++r) s += UN[r][i]*K[r][j];
                T4[i][j] = s;
            }

        // ---------- apply updates (all RHS already materialized) ----------
        // B -= atil*K*G2 + (atil*K*U)^T + U^T N K U ; then symmetrize
        #pragma unroll
        for (int i = 0; i < 4; ++i)
            #pragma unroll
            for (int j = 0; j < 4; ++j) {
                double s = atil[i]*KG2[i][j] + atil[j]*KU[j][i];
                #pragma unroll
                for (int r = 0; r < 4; ++r) s += UN[r][i]*KU[r][j];
                B[i][j] -= s;
            }
        #pragma unroll
        for (int i = 0; i < 4; ++i)
            #pragma unroll
            for (int j = i+1; j < 4; ++j) {
                double v2 = 0.5*(B[i][j] + B[j][i]);
                B[i][j] = v2; B[j][i] = v2;
            }

        // C -= T4 @ V
        #pragma unroll
        for (int i = 0; i < 4; ++i)
            #pragma unroll
            for (int j = 0; j < 4; ++j) {
                double s = 0.0;
                #pragma unroll
                for (int r = 0; r < 4; ++r) s += T4[i][r]*V[r][j];
                C[i][j] -= s;
            }

        // Ps -= V^T diag(Nk) K V ; symmetrize
        #pragma unroll
        for (int i = 0; i < 4; ++i)
            #pragma unroll
            for (int j = 0; j < 4; ++j) {
                double s = 0.0;
                #pragma unroll
                for (int r = 0; r < 4; ++r) s += VN[r][i]*KV[r][j];
                Ps[i][j] -= s;
            }
        #pragma unroll
        for (int i = 0; i < 4; ++i)
            #pragma unroll
            for (int j = i+1; j < 4; ++j) {
                double v2 = 0.5*(Ps[i][j] + Ps[j][i]);
                Ps[i][j] = v2; Ps[j][i] = v2;
            }

        // means + quad
        double Jnu[4];
        #pragma unroll
        for (int k = 0; k < 4; ++k) Jnu[k] = Nk[k]*Knu[k];
        double q = 0.0;
        #pragma unroll
        for (int k = 0; k < 4; ++k) q += nu[k]*Jnu[k];
        sum_quad += q;
        #pragma unroll
        for (int i = 0; i < 4; ++i) {
            double s = 0.0;
            #pragma unroll
            for (int r = 0; r < 4; ++r) s += T4[i][r]*nu[r];
            mu[i] += s;
        }
        #pragma unroll
        for (int c2 = 0; c2 < 4; ++c2) {
            double s = 0.0;
            #pragma unroll
            for (int r = 0; r < 4; ++r) s += V[r][c2]*Jnu[r];
            ms[c2] += s;
        }

        // a <- a*sg2/(a+sg2)
        #pragma unroll
        for (int k = 0; k < 4; ++k) a[k] = a[k] * sg2 * dinv[k];
    }

    // ---------- log-likelihood ----------
    // Sum_t sum_k log d_k(t) telescopes: 1/a_t = 1/a_0 + t/sg2
    double sum_logd = 0.0;
    {
        const double Td = (double)TT;
        const double lgs2 = log(sg2);
        #pragma unroll
        for (int k = 0; k < 4; ++k) {
            double a0k = (k & 1) ? a0c1 : a0c0;
            double ck = sg2 / a0k;
            sum_logd += Td * lgs2 + log(ck + Td) - log(ck);
        }
    }
    const double logdet4 = log(det_m) + det_e * LN2;
    const double ll = -0.5 * ((double)TT * 128.0 * LOG2PI + 32.0 * sum_logd
                              + logdet4 + sum_quad);

    // ---------- 8x8 mean-subspace inverse ----------
    // T8 = [[diag(a)+32B, sqrt(32) C],[sqrt(32) C^T, Ps]] (SPD)
    double T8[8][8], K8[8][8];
    const double rn = 5.6568542494923801952067548968388; // sqrt(32)
    #pragma unroll
    for (int i = 0; i < 8; ++i)
        #pragma unroll
        for (int j = 0; j < 8; ++j) { T8[i][j] = 0.0; K8[i][j] = (i==j)?1.0:0.0; }
    #pragma unroll
    for (int i = 0; i < 4; ++i)
        #pragma unroll
        for (int j = 0; j < 4; ++j) {
            T8[i][j]     = ((i==j)?a[i]:0.0) + 32.0*B[i][j];
            T8[i][4+j]   = rn * C[i][j];
            T8[4+j][i]   = rn * C[i][j];
            T8[4+i][4+j] = Ps[i][j];
        }
    #pragma unroll
    for (int p = 0; p < 8; ++p) {
        double ip = 1.0 / T8[p][p];
        #pragma unroll
        for (int j = 0; j < 8; ++j) { T8[p][j] *= ip; K8[p][j] *= ip; }
        #pragma unroll
        for (int r = 0; r < 8; ++r) {
            if (r == p) continue;
            double f = T8[r][p];
            #pragma unroll
            for (int j = 0; j < 8; ++j) { T8[r][j] -= f*T8[p][j]; K8[r][j] -= f*K8[p][j]; }
        }
    }

    // ---------- publish to LDS, expand ----------
    __shared__ double sTi[8][8];
    __shared__ double sA[4];
    __shared__ double sLL;
    if (threadIdx.x == 0) {
        for (int i = 0; i < 8; ++i)
            for (int j = 0; j < 8; ++j) sTi[i][j] = K8[i][j];
        for (int k = 0; k < 4; ++k) sA[k] = a[k];
        sLL = ll;
    }
    __syncthreads();

    const double inv32 = 1.0/32.0;
    const double invrn = 0.17677669529663688110021109052621; // 1/sqrt(32)
    const int total = 1 + 132*132;
    for (int idx = (int)threadIdx.x; idx < total; idx += 64) {
        double v;
        if (idx == 0) {
            v = sLL;
        } else {
            int el = idx - 1;
            int i = el / 132;
            int j = el - 132*i;
            if (i < 128) {
                int ki = ((i >> 6) << 1) | (i & 1);
                if (j < 128) {
                    int kj = ((j >> 6) << 1) | (j & 1);
                    v = sTi[ki][kj] * inv32;
                    if (ki == kj) {
                        double ia = 1.0 / sA[ki];
                        v -= ia * inv32;
                        if (i == j) v += ia;
                    }
                } else {
                    v = sTi[ki][j - 124] * invrn;       // bias-state block
                }
            } else {
                if (j < 128) {
                    int kj = ((j >> 6) << 1) | (j & 1);
                    v = sTi[kj][i - 124] * invrn;
                } else {
                    v = sTi[i - 124][j - 124];          // state-state block
                }
            }
        }
        out[idx] = (float)v;
    }
}

extern "C" void kernel_launch(void* const* d_in, const int* in_sizes, int n_in,
                              void* d_out, int out_size, void* d_ws, size_t ws_size,
                              hipStream_t stream) {
    (void)in_sizes; (void)n_in; (void)out_size; (void)d_ws; (void)ws_size;
    const float* track       = (const float*)d_in[0];
    const float* bias_scales = (const float*)d_in[1];
    const float* obs_noise   = (const float*)d_in[2];
    const float* trans_noise = (const float*)d_in[3];
    float* out = (float*)d_out;
    hipLaunchKernelGGL(hmm_kernel, dim3(1), dim3(64), 0, stream,
                       track, bias_scales, obs_noise, trans_noise, out);
}

// Round 2
// 186.545 us; speedup vs baseline: 27.0732x; 27.0732x over previous
//
#include <hip/hip_runtime.h>
#include <math.h>

#define TT 2048
#define NTH 256
#define CS 8
#define L2PI 1.8378770664093454835606594728112

// Gaussian potential over (F = first state (4), L = last state (4), B = class-bias means (4)):
// log psi = g + h.x - 0.5 x^T J x
struct Pot {
    double JFF[4][4], JFL[4][4], JFB[4][4];
    double JLL[4][4], JLB[4][4], JBB[4][4];
    double hF[4], hL[4], hB[4];
    double g;
};

struct Cn {
    double qa, qb, qc;   // Qi = Qs^-1 entries: [[qa,0,qb,0],[0,qa,0,qb],[qb,0,qc,0],[0,qb,0,qc]]
    double wa, wb;       // W = F^T Qi rows 2,3 entries: wa=6/qn2, wb=-2/qn2 (rows 0,1 use qa,qb)
    double ri;           // 1/r = 32/sg2
    double Cstep;        // per-step constant: obs + transition normalizers
};

// In-place SPD 4x4 inverse (Gauss-Jordan, no pivoting), destroys A, returns logdet.
__device__ __forceinline__ void inv4d(double A[4][4], double Ai[4][4], double& ldet) {
    #pragma unroll
    for (int i = 0; i < 4; ++i)
        #pragma unroll
        for (int j = 0; j < 4; ++j) Ai[i][j] = (i == j) ? 1.0 : 0.0;
    double ld = 0.0;
    #pragma unroll
    for (int p = 0; p < 4; ++p) {
        double piv = A[p][p];
        ld += log(piv);
        double ip = 1.0 / piv;
        #pragma unroll
        for (int j = 0; j < 4; ++j) { A[p][j] *= ip; Ai[p][j] *= ip; }
        #pragma unroll
        for (int r = 0; r < 4; ++r) {
            if (r == p) continue;
            double f = A[r][p];
            #pragma unroll
            for (int j = 0; j < 4; ++j) { A[r][j] -= f * A[p][j]; Ai[r][j] -= f * Ai[p][j]; }
        }
    }
    ldet = ld;
}

// Single-step potential over (z_t, z_{t+1}, b):
//  N(z'; F z, Qs) * prod_k N(y_k; b_k + z'_{h_k}, r),  y = (x0,x1,x0,x1), h = (0,0,2,2)
__device__ __forceinline__ void init_step(Pot& P, double x0, double x1, const Cn& C) {
    const double qa = C.qa, qb = C.qb, qc = C.qc, wa = C.wa, wb = C.wb, ri = C.ri;
    #pragma unroll
    for (int i = 0; i < 4; ++i)
        #pragma unroll
        for (int j = 0; j < 4; ++j) {
            P.JFF[i][j] = 0.0; P.JFL[i][j] = 0.0; P.JFB[i][j] = 0.0;
            P.JLL[i][j] = 0.0; P.JLB[i][j] = 0.0; P.JBB[i][j] = 0.0;
        }
    // JFF = F^T Qi F
    P.JFF[0][0] = qa; P.JFF[0][2] = wa; P.JFF[2][0] = wa; P.JFF[2][2] = qc;
    P.JFF[1][1] = qa; P.JFF[1][3] = wa; P.JFF[3][1] = wa; P.JFF[3][3] = qc;
    // JFL = -W
    P.JFL[0][0] = -qa; P.JFL[0][2] = -qb;
    P.JFL[1][1] = -qa; P.JFL[1][3] = -qb;
    P.JFL[2][0] = -wa; P.JFL[2][2] = -wb;
    P.JFL[3][1] = -wa; P.JFL[3][3] = -wb;
    // JLL = Qi + 2/r at (0,0),(2,2)
    P.JLL[0][0] = qa + 2.0*ri; P.JLL[0][2] = qb; P.JLL[2][0] = qb; P.JLL[2][2] = qc + 2.0*ri;
    P.JLL[1][1] = qa;          P.JLL[1][3] = qb; P.JLL[3][1] = qb; P.JLL[3][3] = qc;
    // JLB: [h_k][k] = 1/r
    P.JLB[0][0] = ri; P.JLB[0][1] = ri; P.JLB[2][2] = ri; P.JLB[2][3] = ri;
    // JBB = (1/r) I
    P.JBB[0][0] = ri; P.JBB[1][1] = ri; P.JBB[2][2] = ri; P.JBB[3][3] = ri;
    #pragma unroll
    for (int i = 0; i < 4; ++i) { P.hF[i] = 0.0; P.hL[i] = 0.0; P.hB[i] = 0.0; }
    P.hL[0] = ri * (x0 + x1); P.hL[2] = ri * (x0 + x1);
    P.hB[0] = ri * x0; P.hB[1] = ri * x1; P.hB[2] = ri * x0; P.hB[3] = ri * x1;
    P.g = -ri * (x0*x0 + x1*x1) + C.Cstep;
}

// Compose running potential P (over F, m, B) with the step potential for data (x0,x1):
// marginalize m; new L = z_next. Specialized for the step's sparse blocks.
__device__ __forceinline__ void step_compose(Pot& P, double x0, double x1, const Cn& C) {
    const double qa = C.qa, qb = C.qb, qc = C.qc, wa = C.wa, wb = C.wb, ri = C.ri;
    double hm[4], Mb[4][4], S[4][4], Si[4][4], ldS;
    #pragma unroll
    for (int i = 0; i < 4; ++i) hm[i] = P.hL[i];
    #pragma unroll
    for (int i = 0; i < 4; ++i)
        #pragma unroll
        for (int j = 0; j < 4; ++j) Mb[i][j] = P.JLB[i][j];
    // S = JLL + F^T Qi F
    #pragma unroll
    for (int i = 0; i < 4; ++i)
        #pragma unroll
        for (int j = 0; j < 4; ++j) S[i][j] = P.JLL[i][j];
    S[0][0] += qa; S[0][2] += wa; S[2][0] += wa; S[2][2] += qc;
    S[1][1] += qa; S[1][3] += wa; S[3][1] += wa; S[3][3] += qc;
    inv4d(S, Si, ldS);
    // A1 = JFL * Si ; v4 = Si*hm ; C1 = Si*Mb ; SiW = Si*W
    double A1[4][4], v4[4], C1[4][4], SiW[4][4];
    #pragma unroll
    for (int i = 0; i < 4; ++i) {
        #pragma unroll
        for (int j = 0; j < 4; ++j) {
            double s1 = 0.0, s3 = 0.0;
            #pragma unroll
            for (int r = 0; r < 4; ++r) { s1 += P.JFL[i][r] * Si[r][j]; s3 += Si[i][r] * Mb[r][j]; }
            A1[i][j] = s1; C1[i][j] = s3;
        }
        double sv = 0.0;
        #pragma unroll
        for (int r = 0; r < 4; ++r) sv += Si[i][r] * hm[r];
        v4[i] = sv;
        SiW[i][0] = Si[i][0]*qa + Si[i][2]*wa;
        SiW[i][1] = Si[i][1]*qa + Si[i][3]*wa;
        SiW[i][2] = Si[i][0]*qb + Si[i][2]*wb;
        SiW[i][3] = Si[i][1]*qb + Si[i][3]*wb;
    }
    // JFF -= A1 * JFL^T
    #pragma unroll
    for (int i = 0; i < 4; ++i)
        #pragma unroll
        for (int j = 0; j < 4; ++j) {
            double s = 0.0;
            #pragma unroll
            for (int r = 0; r < 4; ++r) s += A1[i][r] * P.JFL[j][r];
            P.JFF[i][j] -= s;
        }
    // JFL = A1 * W   (out.JFL = -JFL*Si*(-W))
    #pragma unroll
    for (int i = 0; i < 4; ++i) {
        double a0 = A1[i][0], a1 = A1[i][1], a2 = A1[i][2], a3 = A1[i][3];
        P.JFL[i][0] = a0*qa + a2*wa;
        P.JFL[i][1] = a1*qa + a3*wa;
        P.JFL[i][2] = a0*qb + a2*wb;
        P.JFL[i][3] = a1*qb + a3*wb;
    }
    // JFB -= A1 * Mb
    #pragma unroll
    for (int i = 0; i < 4; ++i)
        #pragma unroll
        for (int j = 0; j < 4; ++j) {
            double s = 0.0;
            #pragma unroll
            for (int r = 0; r < 4; ++r) s += A1[i][r] * Mb[r][j];
            P.JFB[i][j] -= s;
        }
    // JLL = Qi + D2 - W^T SiW
    {
        double T[4][4];
        #pragma unroll
        for (int j = 0; j < 4; ++j) {
            T[0][j] = qa*SiW[0][j] + wa*SiW[2][j];
            T[1][j] = qa*SiW[1][j] + wa*SiW[3][j];
            T[2][j] = qb*SiW[0][j] + wb*SiW[2][j];
            T[3][j] = qb*SiW[1][j] + wb*SiW[3][j];
        }
        #pragma unroll
        for (int i = 0; i < 4; ++i)
            #pragma unroll
            for (int j = 0; j < 4; ++j) P.JLL[i][j] = -T[i][j];
        P.JLL[0][0] += qa + 2.0*ri; P.JLL[0][2] += qb; P.JLL[2][0] += qb; P.JLL[2][2] += qc + 2.0*ri;
        P.JLL[1][1] += qa;          P.JLL[1][3] += qb; P.JLL[3][1] += qb; P.JLL[3][3] += qc;
    }
    // JLB = Kcb + W^T C1
    #pragma unroll
    for (int j = 0; j < 4; ++j) {
        P.JLB[0][j] = qa*C1[0][j] + wa*C1[2][j];
        P.JLB[1][j] = qa*C1[1][j] + wa*C1[3][j];
        P.JLB[2][j] = qb*C1[0][j] + wb*C1[2][j];
        P.JLB[3][j] = qb*C1[1][j] + wb*C1[3][j];
    }
    P.JLB[0][0] += ri; P.JLB[0][1] += ri; P.JLB[2][2] += ri; P.JLB[2][3] += ri;
    // JBB += ri*I - Mb^T C1
    #pragma unroll
    for (int i = 0; i < 4; ++i)
        #pragma unroll
        for (int j = 0; j < 4; ++j) {
            double s = 0.0;
            #pragma unroll
            for (int r = 0; r < 4; ++r) s += Mb[r][i] * C1[r][j];
            P.JBB[i][j] += ((i == j) ? ri : 0.0) - s;
        }
    // hF -= A1*hm
    #pragma unroll
    for (int i = 0; i < 4; ++i) {
        double s = 0.0;
        #pragma unroll
        for (int r = 0; r < 4; ++r) s += A1[i][r] * hm[r];
        P.hF[i] -= s;
    }
    // hL = kc + W^T v4
    P.hL[0] = ri*(x0+x1) + qa*v4[0] + wa*v4[2];
    P.hL[1] =              qa*v4[1] + wa*v4[3];
    P.hL[2] = ri*(x0+x1) + qb*v4[0] + wb*v4[2];
    P.hL[3] =              qb*v4[1] + wb*v4[3];
    // hB += kb - Mb^T v4
    #pragma unroll
    for (int i = 0; i < 4; ++i) {
        double s = 0.0;
        #pragma unroll
        for (int r = 0; r < 4; ++r) s += Mb[r][i] * v4[r];
        P.hB[i] -= s;
    }
    P.hB[0] += ri*x0; P.hB[1] += ri*x1; P.hB[2] += ri*x0; P.hB[3] += ri*x1;
    // g
    double q = 0.0;
    #pragma unroll
    for (int r = 0; r < 4; ++r) q += hm[r] * v4[r];
    P.g += -ri*(x0*x0 + x1*x1) + C.Cstep + 2.0*L2PI - 0.5*ldS + 0.5*q;
}

// Generic composition: P1 (regs, earlier) o P2 (LDS, later), marginalizing shared middle.
__device__ __forceinline__ void tree_compose(Pot& P1, const Pot* P2) {
    double hm[4], Mb[4][4], S[4][4], Si[4][4], ldS;
    #pragma unroll
    for (int i = 0; i < 4; ++i) hm[i] = P1.hL[i] + P2->hF[i];
    #pragma unroll
    for (int i = 0; i < 4; ++i)
        #pragma unroll
        for (int j = 0; j < 4; ++j) {
            Mb[i][j] = P1.JLB[i][j] + P2->JFB[i][j];
            S[i][j]  = P1.JLL[i][j] + P2->JFF[i][j];
        }
    inv4d(S, Si, ldS);
    double A1[4][4], v4[4], C1[4][4], F2[4][4], B2[4][4];
    #pragma unroll
    for (int i = 0; i < 4; ++i)
        #pragma unroll
        for (int j = 0; j < 4; ++j) F2[i][j] = P2->JFL[i][j];
    #pragma unroll
    for (int i = 0; i < 4; ++i) {
        #pragma unroll
        for (int j = 0; j < 4; ++j) {
            double s1 = 0.0, s3 = 0.0, s4 = 0.0;
            #pragma unroll
            for (int r = 0; r < 4; ++r) {
                s1 += P1.JFL[i][r] * Si[r][j];
                s3 += Si[i][r] * Mb[r][j];
                s4 += Si[i][r] * F2[r][j];
            }
            A1[i][j] = s1; C1[i][j] = s3; B2[i][j] = s4;
        }
        double sv = 0.0;
        #pragma unroll
        for (int r = 0; r < 4; ++r) sv += Si[i][r] * hm[r];
        v4[i] = sv;
    }
    // JFF -= A1*JFL^T
    #pragma unroll
    for (int i = 0; i < 4; ++i)
        #pragma unroll
        for (int j = 0; j < 4; ++j) {
            double s = 0.0;
            #pragma unroll
            for (int r = 0; r < 4; ++r) s += A1[i][r] * P1.JFL[j][r];
            P1.JFF[i][j] -= s;
        }
    // JFL = -A1*F2
    #pragma unroll
    for (int i = 0; i < 4; ++i)
        #pragma unroll
        for (int j = 0; j < 4; ++j) {
            double s = 0.0;
            #pragma unroll
            for (int r = 0; r < 4; ++r) s += A1[i][r] * F2[r][j];
            P1.JFL[i][j] = -s;
        }
    // JFB -= A1*Mb
    #pragma unroll
    for (int i = 0; i < 4; ++i)
        #pragma unroll
        for (int j = 0; j < 4; ++j) {
            double s = 0.0;
            #pragma unroll
            for (int r = 0; r < 4; ++r) s += A1[i][r] * Mb[r][j];
            P1.JFB[i][j] -= s;
        }
    // JLL = P2.JLL - F2^T B2 ; JLB = P2.JLB - F2^T C1 ; JBB += P2.JBB - Mb^T C1
    #pragma unroll
    for (int i = 0; i < 4; ++i)
        #pragma unroll
        for (int j = 0; j < 4; ++j) {
            double s1 = 0.0, s2 = 0.0, s3 = 0.0;
            #pragma unroll
            for (int r = 0; r < 4; ++r) {
                s1 += F2[r][i] * B2[r][j];
                s2 += F2[r][i] * C1[r][j];
                s3 += Mb[r][i] * C1[r][j];
            }
            P1.JLL[i][j] = P2->JLL[i][j] - s1;
            P1.JLB[i][j] = P2->JLB[i][j] - s2;
            P1.JBB[i][j] += P2->JBB[i][j] - s3;
        }
    // h updates
    #pragma unroll
    for (int i = 0; i < 4; ++i) {
        double sa = 0.0, sl = 0.0, sb = 0.0;
        #pragma unroll
        for (int r = 0; r < 4; ++r) {
            sa += A1[i][r] * hm[r];
            sl += F2[r][i] * v4[r];
            sb += Mb[r][i] * v4[r];
        }
        P1.hF[i] -= sa;
        P1.hL[i] = P2->hL[i] - sl;
        P1.hB[i] += P2->hB[i] - sb;
    }
    double q = 0.0;
    #pragma unroll
    for (int r = 0; r < 4; ++r) q += hm[r] * v4[r];
    P1.g += P2->g + 2.0*L2PI - 0.5*ldS + 0.5*q;
}

__device__ __forceinline__ void store_pot(Pot* dst, const Pot& src) {
    #pragma unroll
    for (int i = 0; i < 4; ++i)
        #pragma unroll
        for (int j = 0; j < 4; ++j) {
            dst->JFF[i][j] = src.JFF[i][j]; dst->JFL[i][j] = src.JFL[i][j];
            dst->JFB[i][j] = src.JFB[i][j]; dst->JLL[i][j] = src.JLL[i][j];
            dst->JLB[i][j] = src.JLB[i][j]; dst->JBB[i][j] = src.JBB[i][j];
        }
    #pragma unroll
    for (int i = 0; i < 4; ++i) { dst->hF[i] = src.hF[i]; dst->hL[i] = src.hL[i]; dst->hB[i] = src.hB[i]; }
    dst->g = src.g;
}

__global__ __launch_bounds__(NTH, 1)
void hmm_kernel(const float* __restrict__ track,
                const float* __restrict__ bias_scales,
                const float* __restrict__ obs_noise_p,
                const float* __restrict__ trans_noise_p,
                float* __restrict__ out)
{
    __shared__ Pot spool[64];
    __shared__ double sTi[8][8];
    __shared__ double sA[4];
    __shared__ double sLL;

    const int c = (int)threadIdx.x;
    const double sg2 = (double)obs_noise_p[0] * (double)obs_noise_p[0];
    const double qn2 = (double)trans_noise_p[0] * (double)trans_noise_p[0];
    const double a00 = (double)bias_scales[0];
    const double a01 = (double)bias_scales[1];

    Cn C;
    C.qa = 12.0 / qn2; C.qb = -6.0 / qn2; C.qc = 4.0 / qn2;
    C.wa = 6.0 / qn2;  C.wb = -2.0 / qn2;
    const double r = sg2 / 32.0;
    C.ri = 1.0 / r;
    const double lndetQs = 4.0*log(qn2) - 2.0*log(12.0);
    C.Cstep = -2.0*log(2.0*M_PI*r) - 2.0*L2PI - 0.5*lndetQs;

    // ---------- Phase 1: each thread builds its 8-step chunk potential ----------
    Pot P;
    {
        const int t0 = c * CS;
        init_step(P, (double)track[2*t0], (double)track[2*t0+1], C);
        #pragma unroll 1
        for (int s = 1; s < CS; ++s) {
            const int t = t0 + s;
            step_compose(P, (double)track[2*t], (double)track[2*t+1], C);
        }
    }

    // ---------- Level 1 (256 -> 128), two sub-rounds through 64 LDS slots ----------
    #pragma unroll 1
    for (int grp = 0; grp < 2; ++grp) {
        const int i = c >> 1;
        const bool inrange = (i >= 64*grp) && (i < 64*(grp+1));
        if ((c & 1) && inrange) store_pot(&spool[i & 63], P);
        __syncthreads();
        if (!(c & 1) && inrange) tree_compose(P, &spool[i & 63]);
        __syncthreads();
    }
    // ---------- Levels 2..8 ----------
    #pragma unroll 1
    for (int lvl = 2; lvl <= 8; ++lvl) {
        const int stride = 1 << lvl;
        const int half = stride >> 1;
        const int idx = c >> lvl;
        if ((c & (stride-1)) == half) store_pot(&spool[idx], P);
        __syncthreads();
        if ((c & (stride-1)) == 0) tree_compose(P, &spool[idx]);
        __syncthreads();
    }

    // ---------- Final: priors, marginalize z0, likelihood, publish ----------
    if (c == 0) {
        // priors: s0 ~ N(0, I4); bbar_k ~ N(0, a0_k/32)
        const double a0v[4] = {a00, a01, a00, a01};
        #pragma unroll
        for (int i = 0; i < 4; ++i) { P.JFF[i][i] += 1.0; P.JBB[i][i] += 32.0 / a0v[i]; }
        P.g += -4.0*L2PI + 2.0*log(32.0) - (log(a00) + log(a01));

        double S[4][4], Si[4][4], ldS;
        #pragma unroll
        for (int i = 0; i < 4; ++i)
            #pragma unroll
            for (int j = 0; j < 4; ++j) S[i][j] = P.JFF[i][j];
        inv4d(S, Si, ldS);
        double YL[4][4], YB[4][4], yF[4];
        #pragma unroll
        for (int i = 0; i < 4; ++i) {
            #pragma unroll
            for (int j = 0; j < 4; ++j) {
                double s1 = 0.0, s2 = 0.0;
                #pragma unroll
                for (int rr = 0; rr < 4; ++rr) { s1 += Si[i][rr]*P.JFL[rr][j]; s2 += Si[i][rr]*P.JFB[rr][j]; }
                YL[i][j] = s1; YB[i][j] = s2;
            }
            double sv = 0.0;
            #pragma unroll
            for (int rr = 0; rr < 4; ++rr) sv += Si[i][rr]*P.hF[rr];
            yF[i] = sv;
        }
        double J8[8][8], h8[8];
        #pragma unroll
        for (int i = 0; i < 4; ++i)
            #pragma unroll
            for (int j = 0; j < 4; ++j) {
                double s1 = 0.0, s2 = 0.0, s3 = 0.0;
                #pragma unroll
                for (int rr = 0; rr < 4; ++rr) {
                    s1 += P.JFL[rr][i]*YL[rr][j];
                    s2 += P.JFL[rr][i]*YB[rr][j];
                    s3 += P.JFB[rr][i]*YB[rr][j];
                }
                J8[i][j]     = P.JLL[i][j] - s1;   // (s, s)
                J8[i][4+j]   = P.JLB[i][j] - s2;   // (s, b)
                J8[4+j][i]   = J8[i][4+j];
                J8[4+i][4+j] = P.JBB[i][j] - s3;   // (b, b)
            }
        #pragma unroll
        for (int i = 0; i < 4; ++i) {
            double s1 = 0.0, s2 = 0.0;
            #pragma unroll
            for (int rr = 0; rr < 4; ++rr) { s1 += P.JFL[rr][i]*yF[rr]; s2 += P.JFB[rr][i]*yF[rr]; }
            h8[i]   = P.hL[i] - s1;
            h8[4+i] = P.hB[i] - s2;
        }
        double qF = 0.0;
        #pragma unroll
        for (int rr = 0; rr < 4; ++rr) qF += P.hF[rr]*yF[rr];
        double g8 = P.g + 2.0*L2PI - 0.5*ldS + 0.5*qF;

        // 8x8 GJ inverse with logdet (SPD)
        double A8[8][8], K8[8][8], ld8 = 0.0;
        #pragma unroll
        for (int i = 0; i < 8; ++i)
            #pragma unroll
            for (int j = 0; j < 8; ++j) { A8[i][j] = J8[i][j]; K8[i][j] = (i==j)?1.0:0.0; }
        #pragma unroll
        for (int p = 0; p < 8; ++p) {
            double piv = A8[p][p];
            ld8 += log(piv);
            double ip = 1.0/piv;
            #pragma unroll
            for (int j = 0; j < 8; ++j) { A8[p][j] *= ip; K8[p][j] *= ip; }
            #pragma unroll
            for (int rr = 0; rr < 8; ++rr) {
                if (rr == p) continue;
                double f = A8[rr][p];
                #pragma unroll
                for (int j = 0; j < 8; ++j) { A8[rr][j] -= f*A8[p][j]; K8[rr][j] -= f*K8[p][j]; }
            }
        }
        double quad = 0.0;
        #pragma unroll
        for (int i = 0; i < 8; ++i) {
            double s = 0.0;
            #pragma unroll
            for (int j = 0; j < 8; ++j) s += K8[i][j]*h8[j];
            quad += h8[i]*s;
        }
        const double ll_mean = g8 + 4.0*L2PI - 0.5*ld8 + 0.5*quad;

        // deviation-subspace evidence (innovations identically zero) + measure constant
        const double Td = (double)TT;
        const double c0 = sg2 / a00, c1 = sg2 / a01;
        const double dev = -31.0*(Td*(L2PI + log(sg2)) + log((c0+Td)/c0))
                           -31.0*(Td*(L2PI + log(sg2)) + log((c1+Td)/c1));
        const double cst = -2.0*Td*log(32.0);
        sLL = ll_mean + dev + cst;

        // sTi = precision of (sqrt(32) bbar, s): bias block J8_bb/32, cross /sqrt(32), state as-is
        const double i32 = 1.0/32.0, irn = 0.17677669529663688110021109052621;
        #pragma unroll
        for (int i = 0; i < 4; ++i)
            #pragma unroll
            for (int j = 0; j < 4; ++j) {
                sTi[i][j]     = J8[4+i][4+j] * i32;
                sTi[i][4+j]   = J8[4+i][j] * irn;
                sTi[4+j][i]   = J8[4+i][j] * irn;
                sTi[4+i][4+j] = J8[i][j];
            }
        #pragma unroll
        for (int k = 0; k < 4; ++k) {
            double a0k = (k & 1) ? a01 : a00;
            sA[k] = a0k * sg2 / (sg2 + Td * a0k);   // a_T = 1/(1/a0 + T/sg2)
        }
    }
    __syncthreads();

    // ---------- Expand 132x132 precision + ll ----------
    const double inv32 = 1.0/32.0;
    const double invrn = 0.17677669529663688110021109052621; // 1/sqrt(32)
    const int total = 1 + 132*132;
    for (int idx = c; idx < total; idx += NTH) {
        double v;
        if (idx == 0) {
            v = sLL;
        } else {
            int el = idx - 1;
            int i = el / 132;
            int j = el - 132*i;
            if (i < 128) {
                int ki = ((i >> 6) << 1) | (i & 1);
                if (j < 128) {
                    int kj = ((j >> 6) << 1) | (j & 1);
                    v = sTi[ki][kj] * inv32;
                    if (ki == kj) {
                        double ia = 1.0 / sA[ki];
                        v -= ia * inv32;
                        if (i == j) v += ia;
                    }
                } else {
                    v = sTi[ki][j - 124] * invrn;
                }
            } else {
                if (j < 128) {
                    int kj = ((j >> 6) << 1) | (j & 1);
                    v = sTi[kj][i - 124] * invrn;
                } else {
                    v = sTi[i - 124][j - 124];
                }
            }
        }
        out[idx] = (float)v;
    }
}

extern "C" void kernel_launch(void* const* d_in, const int* in_sizes, int n_in,
                              void* d_out, int out_size, void* d_ws, size_t ws_size,
                              hipStream_t stream) {
    (void)in_sizes; (void)n_in; (void)out_size; (void)d_ws; (void)ws_size;
    const float* track       = (const float*)d_in[0];
    const float* bias_scales = (const float*)d_in[1];
    const float* obs_noise   = (const float*)d_in[2];
    const float* trans_noise = (const float*)d_in[3];
    float* out = (float*)d_out;
    hipLaunchKernelGGL(hmm_kernel, dim3(1), dim3(NTH), 0, stream,
                       track, bias_scales, obs_noise, trans_noise, out);
}

// Round 3
// 112.892 us; speedup vs baseline: 44.7362x; 1.6524x over previous
//
#include <hip/hip_runtime.h>
#include <math.h>

#define L2PI 1.8378770664093454835606594728112
#define LN2  0.69314718055994530941723212145818

// ---------------------------------------------------------------------------
// Lane-parallel Gaussian potential over (F = first state(4), L = last state(4),
// B = class-bias means(4)).  16 lanes per potential; lane (i,j) = ((l>>2)&3, l&3)
// holds element (i,j) of each 4x4 J block; h vectors replicated over rows
// (lane (i,j) holds h[j]); g/dm/de replicated.  log psi = g + h.x - 0.5 x'Jx,
// with running det product in (dm, de):  effective g -= 0.5*(log dm + de*ln2).
// ---------------------------------------------------------------------------
struct LP {
    double jFF, jFL, jFB, jLL, jLB, jBB;
    double hF, hL, hB, g, dm, de;
};

struct Cn { double qa, qb, qc, wa, wb, ri, Cstep; };

__device__ __forceinline__ double shf(double v, int s) { return __shfl(v, s, 64); }
__device__ __forceinline__ double sx (double v, int m) { return __shfl_xor(v, m, 64); }
__device__ __forceinline__ double rowsum(double t) { t += sx(t,1); t += sx(t,2); return t; }
__device__ __forceinline__ double colsum(double t) { t += sx(t,4); t += sx(t,8); return t; }

// C = A.B
__device__ __forceinline__ double mm(double A, double B, int gb, int i, int j) {
    double c = 0.0;
    #pragma unroll
    for (int r = 0; r < 4; ++r) c = fma(shf(A, gb+4*i+r), shf(B, gb+4*r+j), c);
    return c;
}
// C = A.B^T
__device__ __forceinline__ double mmBT(double A, double B, int gb, int i, int j) {
    double c = 0.0;
    #pragma unroll
    for (int r = 0; r < 4; ++r) c = fma(shf(A, gb+4*i+r), shf(B, gb+4*j+r), c);
    return c;
}
// C = A^T.B
__device__ __forceinline__ double mmAT(double A, double B, int gb, int i, int j) {
    double c = 0.0;
    #pragma unroll
    for (int r = 0; r < 4; ++r) c = fma(shf(A, gb+4*r+i), shf(B, gb+4*r+j), c);
    return c;
}
// (M.v)[j] replicated (v replicated-j in)
__device__ __forceinline__ double mv_repj(double M, double v, int gb, int j) {
    double y = rowsum(M * v);          // y[i] at row i
    return shf(y, gb + 4*j);           // redistribute to replicated-j
}
// (M^T.v)[j] replicated
__device__ __forceinline__ double mtv_repj(double M, double v, int gb, int i) {
    double vr = shf(v, gb + i);        // v[i]
    return colsum(M * vr);
}
// sum_j a_j b_j, replicated
__device__ __forceinline__ double dot_repj(double a, double b) { return rowsum(a * b); }

// SPD 4x4 inverse via GJ on 16 lanes; det product folded into (dm, de).
__device__ __forceinline__ double inv4(double A, double& dm, double& de, int gb, int i, int j) {
    double K = (i == j) ? 1.0 : 0.0;
    #pragma unroll
    for (int p = 0; p < 4; ++p) {
        double piv = shf(A, gb + 5*p);
        dm *= piv;
        double ip  = 1.0 / piv;
        double Apj = shf(A, gb + 4*p + j) * ip;
        double Kpj = shf(K, gb + 4*p + j) * ip;
        double f   = shf(A, gb + 4*i + p);
        bool isp = (i == p);
        A = isp ? A * ip : fma(-f, Apj, A);
        K = isp ? K * ip : fma(-f, Kpj, K);
    }
    int ex; dm = frexp(dm, &ex); de += (double)ex;
    return K;
}

// Single-step potential: N(z'; F z, Qs) * prod_k N(y_k; b_k + z'_{h_k}, r)
__device__ __forceinline__ LP init_lane(double x0, double x1, const Cn& C, int i, int j) {
    LP P;
    double v = 0.0;
    if (i == j) v = (i < 2) ? C.qa : C.qc;
    if ((i ^ j) == 2) v = C.wa;
    P.jFF = v;
    v = 0.0;
    if (j == (i & 1))     v = (i < 2) ? -C.qa : -C.wa;
    if (j == (i & 1) + 2) v = (i < 2) ? -C.qb : -C.wb;
    P.jFL = v;
    P.jFB = 0.0;
    v = 0.0;
    if (i == j) v = ((i < 2) ? C.qa : C.qc) + (((i & 1) == 0) ? 2.0*C.ri : 0.0);
    if ((i ^ j) == 2) v = C.qb;
    P.jLL = v;
    P.jLB = (((i == 0) && (j < 2)) || ((i == 2) && (j >= 2))) ? C.ri : 0.0;
    P.jBB = (i == j) ? C.ri : 0.0;
    P.hF = 0.0;
    P.hL = ((j & 1) == 0) ? C.ri * (x0 + x1) : 0.0;
    P.hB = C.ri * ((j & 1) ? x1 : x0);
    P.g  = -C.ri * (x0*x0 + x1*x1) + C.Cstep;
    P.dm = 1.0; P.de = 0.0;
    return P;
}

// Compose P1 (earlier) o P2 (later), marginalizing the shared middle state.
__device__ __forceinline__ LP compose(const LP& P1, const LP& P2, int gb, int i, int j) {
    LP R;
    double hm = P1.hL + P2.hF;
    double Mb = P1.jLB + P2.jFB;
    double S  = P1.jLL + P2.jFF;
    double dm = P1.dm * P2.dm;
    double de = P1.de + P2.de;
    { int ex; dm = frexp(dm, &ex); de += (double)ex; }
    double Si = inv4(S, dm, de, gb, i, j);
    double A1 = mm(P1.jFL, Si, gb, i, j);
    double C1 = mm(Si, Mb, gb, i, j);
    double B2 = mm(Si, P2.jFL, gb, i, j);
    double v4 = mv_repj(Si, hm, gb, j);
    R.jFF = P1.jFF - mmBT(A1, P1.jFL, gb, i, j);
    R.jFL = -mm(A1, P2.jFL, gb, i, j);
    R.jFB = P1.jFB - mm(A1, Mb, gb, i, j);
    R.jLL = P2.jLL - mmAT(P2.jFL, B2, gb, i, j);
    R.jLB = P2.jLB - mmAT(P2.jFL, C1, gb, i, j);
    R.jBB = P1.jBB + P2.jBB - mmAT(Mb, C1, gb, i, j);
    R.hF = P1.hF - mv_repj(A1, hm, gb, j);
    R.hL = P2.hL - mtv_repj(P2.jFL, v4, gb, i);
    R.hB = P1.hB + P2.hB - mtv_repj(Mb, v4, gb, i);
    R.g  = P1.g + P2.g + 2.0*L2PI + 0.5 * dot_repj(hm, v4);
    R.dm = dm; R.de = de;
    return R;
}

__device__ __forceinline__ LP fetchx(const LP& P, int m) {
    LP O;
    O.jFF = sx(P.jFF,m); O.jFL = sx(P.jFL,m); O.jFB = sx(P.jFB,m);
    O.jLL = sx(P.jLL,m); O.jLB = sx(P.jLB,m); O.jBB = sx(P.jBB,m);
    O.hF  = sx(P.hF,m);  O.hL  = sx(P.hL,m);  O.hB  = sx(P.hB,m);
    O.g   = sx(P.g,m);   O.dm  = sx(P.dm,m);  O.de  = sx(P.de,m);
    return O;
}
__device__ __forceinline__ LP csel(bool up, const LP& O, const LP& P) {
    LP A;
    A.jFF = up?O.jFF:P.jFF; A.jFL = up?O.jFL:P.jFL; A.jFB = up?O.jFB:P.jFB;
    A.jLL = up?O.jLL:P.jLL; A.jLB = up?O.jLB:P.jLB; A.jBB = up?O.jBB:P.jBB;
    A.hF  = up?O.hF :P.hF;  A.hL  = up?O.hL :P.hL;  A.hB  = up?O.hB :P.hB;
    A.g   = up?O.g  :P.g;   A.dm  = up?O.dm :P.dm;  A.de  = up?O.de :P.de;
    return A;
}
__device__ __forceinline__ void pot_store(double* p, const LP& P) {
    p[0]=P.jFF; p[1]=P.jFL; p[2]=P.jFB; p[3]=P.jLL; p[4]=P.jLB; p[5]=P.jBB;
    p[6]=P.hF;  p[7]=P.hL;  p[8]=P.hB;  p[9]=P.g;   p[10]=P.dm; p[11]=P.de;
}
__device__ __forceinline__ LP pot_load(const double* p) {
    LP P;
    P.jFF=p[0]; P.jFL=p[1]; P.jFB=p[2]; P.jLL=p[3]; P.jLB=p[4]; P.jBB=p[5];
    P.hF=p[6];  P.hL=p[7];  P.hB=p[8];  P.g=p[9];   P.dm=p[10]; P.de=p[11];
    return P;
}

__device__ __forceinline__ Cn make_cn(double sg2, double qn2) {
    Cn C;
    C.qa = 12.0/qn2; C.qb = -6.0/qn2; C.qc = 4.0/qn2;
    C.wa = 6.0/qn2;  C.wb = -2.0/qn2;
    C.ri = 32.0/sg2;
    const double r = sg2/32.0;
    C.Cstep = -2.0*log(2.0*M_PI*r) - 2.0*L2PI - 0.5*(4.0*log(qn2) - 2.0*log(12.0));
    return C;
}

// ---------- K1: 32 blocks x 512 threads; each group of 16 lanes reduces 2 steps;
// butterfly reduce 32 groups/block -> 1 pot per block -> ws ----------
__global__ __launch_bounds__(512)
void hmm_k1(const float* __restrict__ track,
            const float* __restrict__ obs_noise_p,
            const float* __restrict__ trans_noise_p,
            double* __restrict__ ws)
{
    __shared__ double pool[2][8][16][12];
    const int tid = (int)threadIdx.x;
    const int l = tid & 63, w = tid >> 6;
    const int i = (l >> 2) & 3, j = l & 3, gb = l & 48, g = (l >> 4) & 3;

    const double sg2 = (double)obs_noise_p[0] * (double)obs_noise_p[0];
    const double qn2 = (double)trans_noise_p[0] * (double)trans_noise_p[0];
    const Cn C = make_cn(sg2, qn2);

    const int u = (int)blockIdx.x * 32 + w * 4 + g;   // pair index 0..1023
    LP P;
    {
        LP Pa = init_lane((double)track[4*u+0], (double)track[4*u+1], C, i, j);
        LP Pb = init_lane((double)track[4*u+2], (double)track[4*u+3], C, i, j);
        P = compose(Pa, Pb, gb, i, j);
    }
    // in-wave butterfly over 4 groups
    {
        LP O = fetchx(P, 16); bool up = (l & 16) != 0;
        P = compose(csel(up,O,P), csel(up,P,O), gb, i, j);
        O = fetchx(P, 32); up = (l & 32) != 0;
        P = compose(csel(up,O,P), csel(up,P,O), gb, i, j);
    }
    // cross-wave butterfly over 8 waves (double-buffered LDS)
    int buf = 0;
    if (l < 16) pot_store(&pool[0][w][l][0], P);
    for (int s = 1; s <= 4; s <<= 1) {
        __syncthreads();
        LP O = pot_load(&pool[buf][w ^ s][l & 15][0]);
        bool up = (w & s) != 0;
        P = compose(csel(up,O,P), csel(up,P,O), gb, i, j);
        buf ^= 1;
        if (s < 4 && l < 16) pot_store(&pool[buf][w][l][0], P);
    }
    if (w == 0 && l < 16)
        pot_store(ws + ((size_t)blockIdx.x * 16 + l) * 12, P);
}

// ---------- K2: 1 block x 512 threads; reduce 32 pots, finalize, expand ----------
__global__ __launch_bounds__(512)
void hmm_k2(const double* __restrict__ ws,
            const float* __restrict__ bias_scales,
            const float* __restrict__ obs_noise_p,
            float* __restrict__ out)
{
    __shared__ double pool[2][8][16][12];
    __shared__ double sTi[8][8];
    __shared__ double sA[4];
    __shared__ double sLL;
    const int tid = (int)threadIdx.x;
    const int l = tid & 63, w = tid >> 6;
    const int i = (l >> 2) & 3, j = l & 3, gb = l & 48, g = (l >> 4) & 3;
    const int G = w * 4 + g;                 // pot index 0..31

    const double sg2 = (double)obs_noise_p[0] * (double)obs_noise_p[0];
    const double a00 = (double)bias_scales[0];
    const double a01 = (double)bias_scales[1];

    LP P = pot_load(ws + ((size_t)G * 16 + (l & 15)) * 12);
    // in-wave butterfly
    {
        LP O = fetchx(P, 16); bool up = (l & 16) != 0;
        P = compose(csel(up,O,P), csel(up,P,O), gb, i, j);
        O = fetchx(P, 32); up = (l & 32) != 0;
        P = compose(csel(up,O,P), csel(up,P,O), gb, i, j);
    }
    // cross-wave butterfly over 8 waves
    int buf = 0;
    if (l < 16) pot_store(&pool[0][w][l][0], P);
    for (int s = 1; s <= 4; s <<= 1) {
        __syncthreads();
        LP O = pot_load(&pool[buf][w ^ s][l & 15][0]);
        bool up = (w & s) != 0;
        P = compose(csel(up,O,P), csel(up,P,O), gb, i, j);
        buf ^= 1;
        if (s < 4 && l < 16) pot_store(&pool[buf][w][l][0], P);
    }

    // ---------- final stage on wave 0 ----------
    if (w == 0) {
        // priors: s0 ~ N(0, I4); bbar_k ~ N(0, a0_k/32)
        const double a0i = (i & 1) ? a01 : a00;
        P.jFF += (i == j) ? 1.0 : 0.0;
        P.jBB += (i == j) ? 32.0 / a0i : 0.0;
        P.g   += -4.0*L2PI + 2.0*log(32.0) - log(a00) - log(a01);
        double dm = P.dm, de = P.de;
        // marginalize z0 (Schur complement of FF)
        double Si = inv4(P.jFF, dm, de, gb, i, j);
        double YL = mm(Si, P.jFL, gb, i, j);
        double YB = mm(Si, P.jFB, gb, i, j);
        double yF = mv_repj(Si, P.hF, gb, j);
        double J8ss = P.jLL - mmAT(P.jFL, YL, gb, i, j);
        double J8sb = P.jLB - mmAT(P.jFL, YB, gb, i, j);
        double J8bb = P.jBB - mmAT(P.jFB, YB, gb, i, j);
        double h8s = P.hL - mtv_repj(P.jFL, yF, gb, i);
        double h8b = P.hB - mtv_repj(P.jFB, yF, gb, i);
        double qF  = dot_repj(P.hF, yF);
        double g8  = P.g + 2.0*L2PI + 0.5*qF;

        // 8x8 stage across all 64 lanes: lane = (I,J)
        const int I = l >> 3, J = l & 7, i4 = I & 3, j4 = J & 3;
        double ss  = shf(J8ss, 4*i4 + j4);
        double sb  = shf(J8sb, 4*i4 + j4);
        double sbT = shf(J8sb, 4*j4 + i4);
        double bb  = shf(J8bb, 4*i4 + j4);
        double A8 = (I < 4) ? ((J < 4) ? ss : sb) : ((J < 4) ? sbT : bb);
        const double J8sav = A8;
        double h8v = (J < 4) ? shf(h8s, j4) : shf(h8b, j4);   // h8[J]
        double h8r = (I < 4) ? shf(h8s, i4) : shf(h8b, i4);   // h8[I]
        double K8 = (I == J) ? 1.0 : 0.0;
        #pragma unroll
        for (int p = 0; p < 8; ++p) {
            double piv = shf(A8, 9*p);
            dm *= piv; { int ex; dm = frexp(dm, &ex); de += (double)ex; }
            double ip = 1.0 / piv;
            double Ap = shf(A8, 8*p + J) * ip;
            double Kp = shf(K8, 8*p + J) * ip;
            double f  = shf(A8, 8*I + p);
            bool isp = (I == p);
            A8 = isp ? A8 * ip : fma(-f, Ap, A8);
            K8 = isp ? K8 * ip : fma(-f, Kp, K8);
        }
        double tq = h8r * K8 * h8v;
        tq += sx(tq,1); tq += sx(tq,2); tq += sx(tq,4);
        tq += sx(tq,8); tq += sx(tq,16); tq += sx(tq,32);

        double ll = g8 + 4.0*L2PI - 0.5*(log(dm) + de*LN2) + 0.5*tq;
        const double Td = 2048.0;
        const double c0 = sg2/a00, c1 = sg2/a01;
        ll += -31.0*(Td*(L2PI + log(sg2)) + log((c0+Td)/c0))
              -31.0*(Td*(L2PI + log(sg2)) + log((c1+Td)/c1))
              -2.0*Td*log(32.0);

        // publish: sTi = precision over (sqrt(32) bbar, s) rearranged from J8
        const double i32 = 1.0/32.0, irn = 0.17677669529663688110021109052621;
        int a = (I >= 4) ? I - 4 : I + 4;
        int b = (J >= 4) ? J - 4 : J + 4;
        double scale = (I >= 4 && J >= 4) ? i32 : (((I >= 4) != (J >= 4)) ? irn : 1.0);
        sTi[a][b] = J8sav * scale;
        if (l < 4) { double a0k = (l & 1) ? a01 : a00; sA[l] = a0k*sg2/(sg2 + Td*a0k); }
        if (l == 0) sLL = ll;
    }
    __syncthreads();

    // ---------- expand 1 + 132x132 outputs ----------
    const double inv32 = 1.0/32.0;
    const double invrn = 0.17677669529663688110021109052621;
    const int total = 1 + 132*132;
    for (int idx = tid; idx < total; idx += 512) {
        double v;
        if (idx == 0) {
            v = sLL;
        } else {
            int el = idx - 1;
            int r = el / 132;
            int cc = el - 132*r;
            if (r < 128) {
                int ki = ((r >> 6) << 1) | (r & 1);
                if (cc < 128) {
                    int kj = ((cc >> 6) << 1) | (cc & 1);
                    v = sTi[ki][kj] * inv32;
                    if (ki == kj) {
                        double ia = 1.0 / sA[ki];
                        v -= ia * inv32;
                        if (r == cc) v += ia;
                    }
                } else {
                    v = sTi[ki][cc - 124] * invrn;
                }
            } else {
                if (cc < 128) {
                    int kj = ((cc >> 6) << 1) | (cc & 1);
                    v = sTi[kj][r - 124] * invrn;
                } else {
                    v = sTi[r - 124][cc - 124];
                }
            }
        }
        out[idx] = (float)v;
    }
}

extern "C" void kernel_launch(void* const* d_in, const int* in_sizes, int n_in,
                              void* d_out, int out_size, void* d_ws, size_t ws_size,
                              hipStream_t stream) {
    (void)in_sizes; (void)n_in; (void)out_size; (void)ws_size;
    const float* track       = (const float*)d_in[0];
    const float* bias_scales = (const float*)d_in[1];
    const float* obs_noise   = (const float*)d_in[2];
    const float* trans_noise = (const float*)d_in[3];
    float* out = (float*)d_out;
    double* ws = (double*)d_ws;   // 32 pots x 16 lanes x 12 doubles = 48 KB
    hipLaunchKernelGGL(hmm_k1, dim3(32), dim3(512), 0, stream,
                       track, obs_noise, trans_noise, ws);
    hipLaunchKernelGGL(hmm_k2, dim3(1), dim3(512), 0, stream,
                       ws, bias_scales, obs_noise, out);
}

// Round 4
// 104.020 us; speedup vs baseline: 48.5517x; 1.0853x over previous
//
#include <hip/hip_runtime.h>
#include <math.h>

#define L2PI 1.8378770664093454835606594728112
#define LN2  0.69314718055994530941723212145818

// ---------------------------------------------------------------------------
// Lane-parallel Gaussian potential over (F = first state(4), L = last state(4),
// B = class-bias means(4)).  16 lanes per potential; lane (i,j) = ((l>>2)&3, l&3)
// holds element (i,j) of each 4x4 J block; h vectors replicated over rows
// (lane (i,j) holds h[j]); g/dm/de replicated.  log psi = g + h.x - 0.5 x'Jx,
// with running det product in (dm, de):  effective g -= 0.5*(log dm + de*ln2).
// ---------------------------------------------------------------------------
struct LP {
    double jFF, jFL, jFB, jLL, jLB, jBB;
    double hF, hL, hB, g, dm, de;
};

struct Cn { double qa, qb, qc, wa, wb, ri, Cstep; };

__device__ __forceinline__ double shf(double v, int s) { return __shfl(v, s, 64); }
__device__ __forceinline__ double sx (double v, int m) { return __shfl_xor(v, m, 64); }

// Single-step potential: N(z'; F z, Qs) * prod_k N(y_k; b_k + z'_{h_k}, r)
__device__ __forceinline__ LP init_lane(double x0, double x1, const Cn& C, int i, int j) {
    LP P;
    double v = 0.0;
    if (i == j) v = (i < 2) ? C.qa : C.qc;
    if ((i ^ j) == 2) v = C.wa;
    P.jFF = v;
    v = 0.0;
    if (j == (i & 1))     v = (i < 2) ? -C.qa : -C.wa;
    if (j == (i & 1) + 2) v = (i < 2) ? -C.qb : -C.wb;
    P.jFL = v;
    P.jFB = 0.0;
    v = 0.0;
    if (i == j) v = ((i < 2) ? C.qa : C.qc) + (((i & 1) == 0) ? 2.0*C.ri : 0.0);
    if ((i ^ j) == 2) v = C.qb;
    P.jLL = v;
    P.jLB = (((i == 0) && (j < 2)) || ((i == 2) && (j >= 2))) ? C.ri : 0.0;
    P.jBB = (i == j) ? C.ri : 0.0;
    P.hF = 0.0;
    P.hL = ((j & 1) == 0) ? C.ri * (x0 + x1) : 0.0;
    P.hB = C.ri * ((j & 1) ? x1 : x0);
    P.g  = -C.ri * (x0*x0 + x1*x1) + C.Cstep;
    P.dm = 1.0; P.de = 0.0;
    return P;
}

// Compose P1 (earlier) o P2 (later), marginalizing the shared middle state.
// Hoisted-broadcast version: 69 double-shuffles total.
__device__ __forceinline__ LP compose(const LP& P1, const LP& P2, int gb, int i, int j) {
    double hm = P1.hL + P2.hF;
    double Mb = P1.jLB + P2.jFB;
    double S  = P1.jLL + P2.jFF;
    double dm = P1.dm * P2.dm;
    double de = P1.de + P2.de;
    { int ex; dm = frexp(dm, &ex); de += (double)ex; }
    // GJ inverse of SPD S (pivots positive); det folded into dm/de
    double K = (i == j) ? 1.0 : 0.0;
    #pragma unroll
    for (int p = 0; p < 4; ++p) {
        double piv = shf(S, gb + 5*p);
        dm *= piv;
        double ip  = 1.0 / piv;
        double Apj = shf(S, gb + 4*p + j) * ip;
        double Kpj = shf(K, gb + 4*p + j) * ip;
        double f   = shf(S, gb + 4*i + p);
        bool isp = (i == p);
        S = isp ? S * ip : fma(-f, Apj, S);
        K = isp ? K * ip : fma(-f, Kpj, K);
    }
    { int ex; dm = frexp(dm, &ex); de += (double)ex; }
    const double Si = K;
    // hoisted broadcasts (shared across all products)
    double sr[4], sc[4], f1r[4], f1T[4], f2c[4], f2T[4], mc[4], mT[4], hmc[4];
    #pragma unroll
    for (int r = 0; r < 4; ++r) {
        sr[r]  = shf(Si, gb + 4*i + r);       // Si(i,r)
        sc[r]  = shf(Si, gb + 4*r + j);       // Si(r,j)
        f1r[r] = shf(P1.jFL, gb + 4*i + r);   // JFL1(i,r)
        f1T[r] = shf(P1.jFL, gb + 4*j + r);   // JFL1(j,r)
        f2c[r] = shf(P2.jFL, gb + 4*r + j);   // JFL2(r,j)
        f2T[r] = shf(P2.jFL, gb + 4*r + i);   // JFL2(r,i)
        mc[r]  = shf(Mb, gb + 4*r + j);       // Mb(r,j)
        mT[r]  = shf(Mb, gb + 4*r + i);       // Mb(r,i)
        hmc[r] = shf(hm, gb + 5*r);           // hm[r]
    }
    double A1 = 0.0, C1 = 0.0, B2 = 0.0, v4i = 0.0;
    #pragma unroll
    for (int r = 0; r < 4; ++r) {
        A1  = fma(f1r[r], sc[r], A1);         // (JFL1.Si)(i,j)
        C1  = fma(sr[r], mc[r], C1);          // (Si.Mb)(i,j)
        B2  = fma(sr[r], f2c[r], B2);         // (Si.JFL2)(i,j)
        v4i = fma(sr[r], hmc[r], v4i);        // (Si.hm)_i  (replicated over j)
    }
    double a1r[4], c1c[4], b2c[4], v4c[4];
    #pragma unroll
    for (int r = 0; r < 4; ++r) {
        a1r[r] = shf(A1, gb + 4*i + r);       // A1(i,r)
        c1c[r] = shf(C1, gb + 4*r + j);       // C1(r,j)
        b2c[r] = shf(B2, gb + 4*r + j);       // B2(r,j)
        v4c[r] = shf(v4i, gb + 5*r);          // v4[r]
    }
    double s_ff=0, s_fl=0, s_fb=0, s_ll=0, s_lb=0, s_bb=0, s_hf=0, s_hl=0, s_hb=0, s_g=0;
    #pragma unroll
    for (int r = 0; r < 4; ++r) {
        s_ff = fma(a1r[r], f1T[r], s_ff);     // (A1.JFL1^T)(i,j)
        s_fl = fma(a1r[r], f2c[r], s_fl);     // (A1.JFL2)(i,j)
        s_fb = fma(a1r[r], mc[r],  s_fb);     // (A1.Mb)(i,j)
        s_ll = fma(f2T[r], b2c[r], s_ll);     // (JFL2^T.B2)(i,j)
        s_lb = fma(f2T[r], c1c[r], s_lb);     // (JFL2^T.C1)(i,j)
        s_bb = fma(mT[r],  c1c[r], s_bb);     // (Mb^T.C1)(i,j)
        s_hf = fma(a1r[r], hmc[r], s_hf);     // (A1.hm)_i
        s_hl = fma(f2c[r], v4c[r], s_hl);     // (JFL2^T.v4)_j
        s_hb = fma(mc[r],  v4c[r], s_hb);     // (Mb^T.v4)_j
        s_g  = fma(hmc[r], v4c[r], s_g);      // hm.v4
    }
    LP R;
    R.jFF = P1.jFF - s_ff;
    R.jFL = -s_fl;
    R.jFB = P1.jFB - s_fb;
    R.jLL = P2.jLL - s_ll;
    R.jLB = P2.jLB - s_lb;
    R.jBB = P1.jBB + P2.jBB - s_bb;
    R.hF  = P1.hF - shf(s_hf, gb + 5*j);      // redistribute (A1 hm)_i -> index by j
    R.hL  = P2.hL - s_hl;
    R.hB  = P1.hB + P2.hB - s_hb;
    R.g   = P1.g + P2.g + 2.0*L2PI + 0.5*s_g;
    R.dm = dm; R.de = de;
    return R;
}

__device__ __forceinline__ LP fetchx(const LP& P, int m) {
    LP O;
    O.jFF = sx(P.jFF,m); O.jFL = sx(P.jFL,m); O.jFB = sx(P.jFB,m);
    O.jLL = sx(P.jLL,m); O.jLB = sx(P.jLB,m); O.jBB = sx(P.jBB,m);
    O.hF  = sx(P.hF,m);  O.hL  = sx(P.hL,m);  O.hB  = sx(P.hB,m);
    O.g   = sx(P.g,m);   O.dm  = sx(P.dm,m);  O.de  = sx(P.de,m);
    return O;
}
__device__ __forceinline__ LP csel(bool up, const LP& O, const LP& P) {
    LP A;
    A.jFF = up?O.jFF:P.jFF; A.jFL = up?O.jFL:P.jFL; A.jFB = up?O.jFB:P.jFB;
    A.jLL = up?O.jLL:P.jLL; A.jLB = up?O.jLB:P.jLB; A.jBB = up?O.jBB:P.jBB;
    A.hF  = up?O.hF :P.hF;  A.hL  = up?O.hL :P.hL;  A.hB  = up?O.hB :P.hB;
    A.g   = up?O.g  :P.g;   A.dm  = up?O.dm :P.dm;  A.de  = up?O.de :P.de;
    return A;
}
__device__ __forceinline__ void pot_store(double* p, const LP& P) {
    p[0]=P.jFF; p[1]=P.jFL; p[2]=P.jFB; p[3]=P.jLL; p[4]=P.jLB; p[5]=P.jBB;
    p[6]=P.hF;  p[7]=P.hL;  p[8]=P.hB;  p[9]=P.g;   p[10]=P.dm; p[11]=P.de;
}
__device__ __forceinline__ LP pot_load(const double* p) {
    LP P;
    P.jFF=p[0]; P.jFL=p[1]; P.jFB=p[2]; P.jLL=p[3]; P.jLB=p[4]; P.jBB=p[5];
    P.hF=p[6];  P.hL=p[7];  P.hB=p[8];  P.g=p[9];   P.dm=p[10]; P.de=p[11];
    return P;
}

__device__ __forceinline__ Cn make_cn(double sg2, double qn2) {
    Cn C;
    C.qa = 12.0/qn2; C.qb = -6.0/qn2; C.qc = 4.0/qn2;
    C.wa = 6.0/qn2;  C.wb = -2.0/qn2;
    C.ri = 32.0/sg2;
    const double r = sg2/32.0;
    C.Cstep = -2.0*log(2.0*M_PI*r) - 2.0*L2PI - 0.5*(4.0*log(qn2) - 2.0*log(12.0));
    return C;
}

// ---------- K1: 64 blocks x 128 threads (2 waves); 8 groups/block, 512 groups
// x 4 steps each; depth-2 register tree + 2 in-wave + 1 cross-wave level ->
// 64 chunk pots (32 steps each) to ws ----------
__global__ __launch_bounds__(128)
void hmm_k1(const float* __restrict__ track,
            const float* __restrict__ obs_noise_p,
            const float* __restrict__ trans_noise_p,
            double* __restrict__ ws)
{
    __shared__ double pool[2][16][13];
    const int tid = (int)threadIdx.x;
    const int l = tid & 63, w = tid >> 6;
    const int i = (l >> 2) & 3, j = l & 3, gb = l & 48, g = (l >> 4) & 3;

    const double sg2 = (double)obs_noise_p[0] * (double)obs_noise_p[0];
    const double qn2 = (double)trans_noise_p[0] * (double)trans_noise_p[0];
    const Cn C = make_cn(sg2, qn2);

    const int G = (int)blockIdx.x * 8 + w * 4 + g;   // group 0..511, 4 steps each
    const int t0 = G * 4;
    LP P;
    {
        LP p0 = init_lane((double)track[2*t0+0], (double)track[2*t0+1], C, i, j);
        LP p1 = init_lane((double)track[2*t0+2], (double)track[2*t0+3], C, i, j);
        LP q0 = compose(p0, p1, gb, i, j);
        LP p2 = init_lane((double)track[2*t0+4], (double)track[2*t0+5], C, i, j);
        LP p3 = init_lane((double)track[2*t0+6], (double)track[2*t0+7], C, i, j);
        LP q1 = compose(p2, p3, gb, i, j);
        P = compose(q0, q1, gb, i, j);
    }
    // in-wave butterfly over 4 groups (time strides 1 then 2)
    {
        LP O = fetchx(P, 16); bool up = (l & 16) != 0;
        P = compose(csel(up,O,P), csel(up,P,O), gb, i, j);
        O = fetchx(P, 32); up = (l & 32) != 0;
        P = compose(csel(up,O,P), csel(up,P,O), gb, i, j);
    }
    // cross-wave level (2 waves, time stride 4)
    if (l < 16) pot_store(&pool[w][l][0], P);
    __syncthreads();
    {
        LP O = pot_load(&pool[w ^ 1][l & 15][0]);
        bool up = (w & 1) != 0;
        P = compose(csel(up,O,P), csel(up,P,O), gb, i, j);
    }
    if (w == 0 && l < 16)
        pot_store(ws + ((size_t)blockIdx.x * 16 + l) * 12, P);
}

// ---------- K2: 1 block x 256 threads; waves 0-1 reduce 64 pots
// (8 groups x 8 pots: 7 composes + 2 in-wave + 1 cross-wave), wave 0
// finalizes, all 256 expand ----------
__global__ __launch_bounds__(256)
void hmm_k2(const double* __restrict__ ws,
            const float* __restrict__ bias_scales,
            const float* __restrict__ obs_noise_p,
            float* __restrict__ out)
{
    __shared__ double pool[2][16][13];
    __shared__ double sTi[8][8];
    __shared__ double sA[4];
    __shared__ double sLL;
    const int tid = (int)threadIdx.x;
    const int l = tid & 63, w = tid >> 6;
    const int i = (l >> 2) & 3, j = l & 3, gb = l & 48, g = (l >> 4) & 3;

    const double sg2 = (double)obs_noise_p[0] * (double)obs_noise_p[0];
    const double a00 = (double)bias_scales[0];
    const double a01 = (double)bias_scales[1];

    LP P;
    if (w < 2) {
        const int G = w * 4 + g;                 // chunk 0..7, pots 8G..8G+7
        const size_t base = (size_t)G * 8 * 16 + (size_t)(l & 15);
        // semi-tree over 8 time-ordered pots
        LP q0, q1, r0, r1;
        q0 = compose(pot_load(ws + (base + 0*16)*12), pot_load(ws + (base + 1*16)*12), gb, i, j);
        q1 = compose(pot_load(ws + (base + 2*16)*12), pot_load(ws + (base + 3*16)*12), gb, i, j);
        r0 = compose(q0, q1, gb, i, j);
        q0 = compose(pot_load(ws + (base + 4*16)*12), pot_load(ws + (base + 5*16)*12), gb, i, j);
        q1 = compose(pot_load(ws + (base + 6*16)*12), pot_load(ws + (base + 7*16)*12), gb, i, j);
        r1 = compose(q0, q1, gb, i, j);
        P = compose(r0, r1, gb, i, j);
        // in-wave butterfly (4 groups)
        LP O = fetchx(P, 16); bool up = (l & 16) != 0;
        P = compose(csel(up,O,P), csel(up,P,O), gb, i, j);
        O = fetchx(P, 32); up = (l & 32) != 0;
        P = compose(csel(up,O,P), csel(up,P,O), gb, i, j);
        if (l < 16) pot_store(&pool[w][l][0], P);
    }
    __syncthreads();
    if (w < 2) {
        LP O = pot_load(&pool[w ^ 1][l & 15][0]);
        bool up = (w & 1) != 0;
        P = compose(csel(up,O,P), csel(up,P,O), gb, i, j);
    }

    // ---------- final stage on wave 0 ----------
    if (w == 0) {
        // priors: s0 ~ N(0, I4); bbar_k ~ N(0, a0_k/32)
        const double a0i = (i & 1) ? a01 : a00;
        P.jFF += (i == j) ? 1.0 : 0.0;
        P.jBB += (i == j) ? 32.0 / a0i : 0.0;
        P.g   += -4.0*L2PI + 2.0*log(32.0) - log(a00) - log(a01);
        double dm = P.dm, de = P.de;
        // marginalize z0: GJ inverse of jFF
        double K = (i == j) ? 1.0 : 0.0;
        double S = P.jFF;
        #pragma unroll
        for (int p = 0; p < 4; ++p) {
            double piv = shf(S, gb + 5*p);
            dm *= piv;
            double ip  = 1.0 / piv;
            double Apj = shf(S, gb + 4*p + j) * ip;
            double Kpj = shf(K, gb + 4*p + j) * ip;
            double f   = shf(S, gb + 4*i + p);
            bool isp = (i == p);
            S = isp ? S * ip : fma(-f, Apj, S);
            K = isp ? K * ip : fma(-f, Kpj, K);
        }
        { int ex; dm = frexp(dm, &ex); de += (double)ex; }
        const double Si = K;
        double sr[4], sc[4], fr[4], fT[4], bc[4], bT[4], hfc[4];
        #pragma unroll
        for (int r = 0; r < 4; ++r) {
            sr[r]  = shf(Si, gb + 4*i + r);
            sc[r]  = shf(Si, gb + 4*r + j);
            fr[r]  = shf(P.jFL, gb + 4*r + i);   // JFL(r,i)
            fT[r]  = shf(P.jFL, gb + 4*r + j);   // JFL(r,j)
            bc[r]  = shf(P.jFB, gb + 4*r + i);   // JFB(r,i)
            bT[r]  = shf(P.jFB, gb + 4*r + j);   // JFB(r,j)
            hfc[r] = shf(P.hF, gb + 5*r);        // hF[r]
        }
        // YL = Si.JFL, YB = Si.JFB, yF_i = (Si.hF)_i
        double YL = 0.0, YB = 0.0, yFi = 0.0;
        #pragma unroll
        for (int r = 0; r < 4; ++r) {
            YL  = fma(sr[r], fT[r], YL);
            YB  = fma(sr[r], bT[r], YB);
            yFi = fma(sr[r], hfc[r], yFi);
        }
        double ylc[4], ybc[4], yfc[4];
        #pragma unroll
        for (int r = 0; r < 4; ++r) {
            ylc[r] = shf(YL, gb + 4*r + j);      // YL(r,j)
            ybc[r] = shf(YB, gb + 4*r + j);      // YB(r,j)
            yfc[r] = shf(yFi, gb + 5*r);         // yF[r]
        }
        double s1 = 0.0, s2 = 0.0, s3 = 0.0, sh1 = 0.0, sh2 = 0.0, qF = 0.0;
        #pragma unroll
        for (int r = 0; r < 4; ++r) {
            s1  = fma(fr[r], ylc[r], s1);        // (JFL^T.YL)(i,j)
            s2  = fma(fr[r], ybc[r], s2);        // (JFL^T.YB)(i,j)
            s3  = fma(bc[r], ybc[r], s3);        // (JFB^T.YB)(i,j)
            sh1 = fma(fT[r], yfc[r], sh1);       // (JFL^T.yF)_j
            sh2 = fma(bT[r], yfc[r], sh2);       // (JFB^T.yF)_j
            qF  = fma(hfc[r], yfc[r], qF);       // hF.yF
        }
        double J8ss = P.jLL - s1;
        double J8sb = P.jLB - s2;
        double J8bb = P.jBB - s3;
        double h8s  = P.hL - sh1;
        double h8b  = P.hB - sh2;
        double g8   = P.g + 2.0*L2PI + 0.5*qF;

        // 8x8 stage across all 64 lanes: lane = (I,J)
        const int I = l >> 3, J = l & 7, i4 = I & 3, j4 = J & 3;
        double ss  = shf(J8ss, 4*i4 + j4);
        double sb  = shf(J8sb, 4*i4 + j4);
        double sbT = shf(J8sb, 4*j4 + i4);
        double bb  = shf(J8bb, 4*i4 + j4);
        double A8 = (I < 4) ? ((J < 4) ? ss : sb) : ((J < 4) ? sbT : bb);
        const double J8sav = A8;
        double h8v = (J < 4) ? shf(h8s, j4) : shf(h8b, j4);   // h8[J]
        double h8r = (I < 4) ? shf(h8s, i4) : shf(h8b, i4);   // h8[I]
        double K8 = (I == J) ? 1.0 : 0.0;
        #pragma unroll
        for (int p = 0; p < 8; ++p) {
            double piv = shf(A8, 9*p);
            dm *= piv; { int ex; dm = frexp(dm, &ex); de += (double)ex; }
            double ip = 1.0 / piv;
            double Ap = shf(A8, 8*p + J) * ip;
            double Kp = shf(K8, 8*p + J) * ip;
            double f  = shf(A8, 8*I + p);
            bool isp = (I == p);
            A8 = isp ? A8 * ip : fma(-f, Ap, A8);
            K8 = isp ? K8 * ip : fma(-f, Kp, K8);
        }
        double tq = h8r * K8 * h8v;
        tq += sx(tq,1); tq += sx(tq,2); tq += sx(tq,4);
        tq += sx(tq,8); tq += sx(tq,16); tq += sx(tq,32);

        double ll = g8 + 4.0*L2PI - 0.5*(log(dm) + de*LN2) + 0.5*tq;
        const double Td = 2048.0;
        const double c0 = sg2/a00, c1 = sg2/a01;
        ll += -31.0*(Td*(L2PI + log(sg2)) + log((c0+Td)/c0))
              -31.0*(Td*(L2PI + log(sg2)) + log((c1+Td)/c1))
              -2.0*Td*log(32.0);

        // publish: sTi = precision over (sqrt(32) bbar, s) rearranged from J8
        const double i32 = 1.0/32.0, irn = 0.17677669529663688110021109052621;
        int a = (I >= 4) ? I - 4 : I + 4;
        int b = (J >= 4) ? J - 4 : J + 4;
        double scale = (I >= 4 && J >= 4) ? i32 : (((I >= 4) != (J >= 4)) ? irn : 1.0);
        sTi[a][b] = J8sav * scale;
        if (l < 4) { double a0k = (l & 1) ? a01 : a00; sA[l] = a0k*sg2/(sg2 + Td*a0k); }
        if (l == 0) sLL = ll;
    }
    __syncthreads();

    // ---------- expand 1 + 132x132 outputs ----------
    const double inv32 = 1.0/32.0;
    const double invrn = 0.17677669529663688110021109052621;
    const int total = 1 + 132*132;
    for (int idx = tid; idx < total; idx += 256) {
        double v;
        if (idx == 0) {
            v = sLL;
        } else {
            int el = idx - 1;
            int r = el / 132;
            int cc = el - 132*r;
            if (r < 128) {
                int ki = ((r >> 6) << 1) | (r & 1);
                if (cc < 128) {
                    int kj = ((cc >> 6) << 1) | (cc & 1);
                    v = sTi[ki][kj] * inv32;
                    if (ki == kj) {
                        double ia = 1.0 / sA[ki];
                        v -= ia * inv32;
                        if (r == cc) v += ia;
                    }
                } else {
                    v = sTi[ki][cc - 124] * invrn;
                }
            } else {
                if (cc < 128) {
                    int kj = ((cc >> 6) << 1) | (cc & 1);
                    v = sTi[kj][r - 124] * invrn;
                } else {
                    v = sTi[r - 124][cc - 124];
                }
            }
        }
        out[idx] = (float)v;
    }
}

extern "C" void kernel_launch(void* const* d_in, const int* in_sizes, int n_in,
                              void* d_out, int out_size, void* d_ws, size_t ws_size,
                              hipStream_t stream) {
    (void)in_sizes; (void)n_in; (void)out_size; (void)ws_size;
    const float* track       = (const float*)d_in[0];
    const float* bias_scales = (const float*)d_in[1];
    const float* obs_noise   = (const float*)d_in[2];
    const float* trans_noise = (const float*)d_in[3];
    float* out = (float*)d_out;
    double* ws = (double*)d_ws;   // 64 pots x 16 lanes x 12 doubles = 96 KB
    hipLaunchKernelGGL(hmm_k1, dim3(64), dim3(128), 0, stream,
                       track, obs_noise, trans_noise, ws);
    hipLaunchKernelGGL(hmm_k2, dim3(1), dim3(256), 0, stream,
                       ws, bias_scales, obs_noise, out);
}